// Round 1
// baseline (5626.483 us; speedup 1.0000x reference)
//
#include <hip/hip_runtime.h>

#define B_SZ 16384
#define D_SZ 1024
#define F_SZ 8192
#define K_TOP 30

// ---------------------------------------------------------------------------
// Transpose dec_w [D, F] -> dec_wT [F, D]  (32x32 LDS tiles)
// ---------------------------------------------------------------------------
__global__ __launch_bounds__(256) void transpose_kernel(const float* __restrict__ in,
                                                        float* __restrict__ out) {
  __shared__ float tile[32][33];
  const int bx = blockIdx.x * 32;  // F dim
  const int by = blockIdx.y * 32;  // D dim
  const int tx = threadIdx.x & 31;
  const int ty = threadIdx.x >> 5;  // 0..7
#pragma unroll
  for (int r = 0; r < 32; r += 8)
    tile[ty + r][tx] = in[(size_t)(by + ty + r) * F_SZ + bx + tx];
  __syncthreads();
#pragma unroll
  for (int r = 0; r < 32; r += 8)
    out[(size_t)(bx + ty + r) * D_SZ + by + tx] = tile[tx][ty + r];
}

// ---------------------------------------------------------------------------
// Encode GEMM: pre[b,f] = sum_d (x[b,d] - dec_b[d]) * enc_w[f,d] + enc_b[f]
// C[16384, 8192] = A[16384,1024] * W[8192,1024]^T   (NT, K contiguous both)
// 128x128 tile, BK=16, 256 threads, 8x8 micro-tile per thread.
// ---------------------------------------------------------------------------
#define BM 128
#define BN 128
#define BK 16
#define LDP (BM + 4)  // pad: stride 132 floats -> 2-way max bank aliasing (free)

__global__ __launch_bounds__(256) void encode_gemm(const float* __restrict__ x,
                                                   const float* __restrict__ enc_w,
                                                   const float* __restrict__ enc_b,
                                                   const float* __restrict__ dec_b,
                                                   float* __restrict__ pre) {
  __shared__ float As[BK][LDP];
  __shared__ float Ws[BK][LDP];
  const int tid = threadIdx.x;
  const int tx = tid & 15;   // 16 cols of threads
  const int ty = tid >> 4;   // 16 rows of threads
  const int rb = blockIdx.y * BM;
  const int cb = blockIdx.x * BN;
  // staging: each thread loads 2 float4 per operand per k-tile
  const int lm = tid >> 2;         // 0..63
  const int lk = (tid & 3) * 4;    // 0,4,8,12

  float acc[8][8];
#pragma unroll
  for (int i = 0; i < 8; i++)
#pragma unroll
    for (int j = 0; j < 8; j++) acc[i][j] = 0.f;

  const float* xa = x + (size_t)(rb + lm) * D_SZ + lk;
  const float* xb = x + (size_t)(rb + lm + 64) * D_SZ + lk;
  const float* wa = enc_w + (size_t)(cb + lm) * D_SZ + lk;
  const float* wb = enc_w + (size_t)(cb + lm + 64) * D_SZ + lk;

  for (int kt = 0; kt < D_SZ; kt += BK) {
    float4 a0 = *(const float4*)(xa + kt);
    float4 a1 = *(const float4*)(xb + kt);
    float4 w0 = *(const float4*)(wa + kt);
    float4 w1 = *(const float4*)(wb + kt);
    float4 db = *(const float4*)(dec_b + kt + lk);
    a0.x -= db.x; a0.y -= db.y; a0.z -= db.z; a0.w -= db.w;
    a1.x -= db.x; a1.y -= db.y; a1.z -= db.z; a1.w -= db.w;
    __syncthreads();  // previous iteration's LDS reads done
    As[lk + 0][lm] = a0.x; As[lk + 1][lm] = a0.y;
    As[lk + 2][lm] = a0.z; As[lk + 3][lm] = a0.w;
    As[lk + 0][lm + 64] = a1.x; As[lk + 1][lm + 64] = a1.y;
    As[lk + 2][lm + 64] = a1.z; As[lk + 3][lm + 64] = a1.w;
    Ws[lk + 0][lm] = w0.x; Ws[lk + 1][lm] = w0.y;
    Ws[lk + 2][lm] = w0.z; Ws[lk + 3][lm] = w0.w;
    Ws[lk + 0][lm + 64] = w1.x; Ws[lk + 1][lm + 64] = w1.y;
    Ws[lk + 2][lm + 64] = w1.z; Ws[lk + 3][lm + 64] = w1.w;
    __syncthreads();
#pragma unroll
    for (int kk = 0; kk < BK; kk++) {
      float a_[8], w_[8];
      *(float4*)&a_[0] = *(const float4*)&As[kk][ty * 8];
      *(float4*)&a_[4] = *(const float4*)&As[kk][ty * 8 + 4];
      *(float4*)&w_[0] = *(const float4*)&Ws[kk][tx * 4];        // cols tx*4..+3
      *(float4*)&w_[4] = *(const float4*)&Ws[kk][tx * 4 + 64];   // cols 64+tx*4..+3
#pragma unroll
      for (int i = 0; i < 8; i++)
#pragma unroll
        for (int j = 0; j < 8; j++) acc[i][j] += a_[i] * w_[j];
    }
  }
  // epilogue: + enc_b, store. Cols: c0 = cb+tx*4 (acc[i][0..3]), c1 = c0+64.
  const int c0 = cb + tx * 4;
  const int c1 = c0 + 64;
  const float4 eb0 = *(const float4*)(enc_b + c0);
  const float4 eb1 = *(const float4*)(enc_b + c1);
#pragma unroll
  for (int i = 0; i < 8; i++) {
    const size_t rowoff = (size_t)(rb + ty * 8 + i) * F_SZ;
    float4 o0, o1;
    o0.x = acc[i][0] + eb0.x; o0.y = acc[i][1] + eb0.y;
    o0.z = acc[i][2] + eb0.z; o0.w = acc[i][3] + eb0.w;
    o1.x = acc[i][4] + eb1.x; o1.y = acc[i][5] + eb1.y;
    o1.z = acc[i][6] + eb1.z; o1.w = acc[i][7] + eb1.w;
    *(float4*)(pre + rowoff + c0) = o0;
    *(float4*)(pre + rowoff + c1) = o1;
  }
}

// ---------------------------------------------------------------------------
// Top-K per row + sparsify in place.
// pre/sparse alias the same buffer (sparse region of d_out).
// Tournament: per-thread chunk max (32 elems), 30x block argmax w/ owner rescan.
// Ties: lower index wins (matches jax.lax.top_k).
// ---------------------------------------------------------------------------
__global__ __launch_bounds__(256) void topk_kernel(float* __restrict__ sparse,
                                                   float* __restrict__ tkv,
                                                   int* __restrict__ tki) {
  __shared__ float row[F_SZ];
  __shared__ float tmax[256];
  __shared__ int targ[256];
  __shared__ float smax[256];
  __shared__ int sarg[256];
  __shared__ float kval[K_TOP];
  __shared__ int kidx[K_TOP];
  const int b = blockIdx.x;
  const int t = threadIdx.x;
  float* prow = sparse + (size_t)b * F_SZ;

  // load row into LDS (float4, coalesced)
#pragma unroll
  for (int q = 0; q < F_SZ / (256 * 4); q++) {
    const int i4 = (q * 256 + t) * 4;
    *(float4*)&row[i4] = *(const float4*)&prow[i4];
  }
  __syncthreads();

  // per-thread chunk max (rotated scan: 2-way bank aliasing only)
  const int base = t * 32;
  {
    float bv = -__builtin_inff();
    int bi = 0x7fffffff;
    for (int j = 0; j < 32; j++) {
      const int idx = base + ((j + t) & 31);
      const float v = row[idx];
      if (v > bv || (v == bv && idx < bi)) { bv = v; bi = idx; }
    }
    tmax[t] = bv; targ[t] = bi;
  }
  __syncthreads();

  for (int k = 0; k < K_TOP; k++) {
    // 256 -> 128 (into smax)
    if (t < 128) {
      float v = tmax[t]; int idx = targ[t];
      const float v2 = tmax[t + 128]; const int i2 = targ[t + 128];
      if (v2 > v || (v2 == v && i2 < idx)) { v = v2; idx = i2; }
      smax[t] = v; sarg[t] = idx;
    }
    __syncthreads();
    // 128 -> 64 -> wave-0 shuffle reduce
    if (t < 64) {
      float v = smax[t]; int idx = sarg[t];
      const float v2 = smax[t + 64]; const int i2 = sarg[t + 64];
      if (v2 > v || (v2 == v && i2 < idx)) { v = v2; idx = i2; }
      for (int off = 32; off > 0; off >>= 1) {
        const float vv = __shfl_down(v, off);
        const int ii = __shfl_down(idx, off);
        if (vv > v || (vv == v && ii < idx)) { v = vv; idx = ii; }
      }
      if (t == 0) { smax[0] = v; sarg[0] = idx; }
    }
    __syncthreads();
    const float gv = smax[0];
    const int gi = sarg[0];
    if (t == 0) {
      const float rv = gv > 0.f ? gv : 0.f;
      kval[k] = rv; kidx[k] = gi;
      tkv[(size_t)b * K_TOP + k] = rv;
      tki[(size_t)b * K_TOP + k] = gi;
    }
    // owner removes winner & rescans its chunk
    if (t == (gi >> 5)) {
      row[gi] = -__builtin_inff();
      float bv = -__builtin_inff();
      int bi = 0x7fffffff;
      for (int j = 0; j < 32; j++) {
        const int idx = base + j;
        const float v = row[idx];
        if (v > bv || (v == bv && idx < bi)) { bv = v; bi = idx; }
      }
      tmax[t] = bv; targ[t] = bi;
    }
    __syncthreads();
  }

  // sparsify: zero LDS row, scatter relu'd winners, stream out
#pragma unroll
  for (int q = 0; q < F_SZ / (256 * 4); q++) {
    const int i4 = (q * 256 + t) * 4;
    *(float4*)&row[i4] = make_float4(0.f, 0.f, 0.f, 0.f);
  }
  __syncthreads();
  if (t < K_TOP) row[kidx[t]] = kval[t];
  __syncthreads();
#pragma unroll
  for (int q = 0; q < F_SZ / (256 * 4); q++) {
    const int i4 = (q * 256 + t) * 4;
    *(float4*)&prow[i4] = *(const float4*)&row[i4];
  }
}

// ---------------------------------------------------------------------------
// Decode: recon[b,:] = dec_b + sum_k v_k * dec_wT[idx_k, :]
// One block per row; thread t owns cols 4t..4t+3.
// ---------------------------------------------------------------------------
__global__ __launch_bounds__(256) void decode_kernel(const float* __restrict__ tkv,
                                                     const int* __restrict__ tki,
                                                     const float* __restrict__ dec_wT,
                                                     const float* __restrict__ dec_b,
                                                     float* __restrict__ recon) {
  __shared__ float kv[K_TOP];
  __shared__ int ki[K_TOP];
  const int b = blockIdx.x;
  const int t = threadIdx.x;
  if (t < K_TOP) {
    kv[t] = tkv[(size_t)b * K_TOP + t];
    ki[t] = tki[(size_t)b * K_TOP + t];
  }
  __syncthreads();
  const int col = t * 4;
  float4 acc = *(const float4*)&dec_b[col];
#pragma unroll 5
  for (int k = 0; k < K_TOP; k++) {
    const float v = kv[k];
    const float4 w = *(const float4*)&dec_wT[(size_t)ki[k] * D_SZ + col];
    acc.x += v * w.x; acc.y += v * w.y; acc.z += v * w.z; acc.w += v * w.w;
  }
  *(float4*)&recon[(size_t)b * D_SZ + col] = acc;
}

// ---------------------------------------------------------------------------
extern "C" void kernel_launch(void* const* d_in, const int* in_sizes, int n_in,
                              void* d_out, int out_size, void* d_ws, size_t ws_size,
                              hipStream_t stream) {
  const float* x     = (const float*)d_in[0];  // [B, D]
  const float* enc_w = (const float*)d_in[1];  // [F, D]
  const float* enc_b = (const float*)d_in[2];  // [F]
  const float* dec_w = (const float*)d_in[3];  // [D, F]
  const float* dec_b = (const float*)d_in[4];  // [D]

  float* recon_out  = (float*)d_out;                        // [B, D]
  float* sparse_out = (float*)d_out + (size_t)B_SZ * D_SZ;  // [B, F]

  // workspace layout (floats): tkv [B*K], tki [B*K], dec_wT [F*D]
  float* tkv    = (float*)d_ws;
  int*   tki    = (int*)((char*)d_ws + (size_t)B_SZ * K_TOP * 4);
  float* dec_wT = (float*)((char*)d_ws + (size_t)2 * B_SZ * K_TOP * 4);

  // 1. transpose dec_w for coalesced decode gathers
  transpose_kernel<<<dim3(F_SZ / 32, D_SZ / 32), 256, 0, stream>>>(dec_w, dec_wT);

  // 2. encode GEMM -> pre_act written into sparse region of d_out
  encode_gemm<<<dim3(F_SZ / BN, B_SZ / BM), 256, 0, stream>>>(x, enc_w, enc_b, dec_b,
                                                              sparse_out);

  // 3. per-row top-K + in-place sparsify
  topk_kernel<<<B_SZ, 256, 0, stream>>>(sparse_out, tkv, tki);

  // 4. sparse decode
  decode_kernel<<<B_SZ, 256, 0, stream>>>(tkv, tki, dec_wT, dec_b, recon_out);
}

// Round 2
// 4282.401 us; speedup vs baseline: 1.3139x; 1.3139x over previous
//
#include <hip/hip_runtime.h>
#include <stdint.h>

#define B_SZ 16384
#define D_SZ 1024
#define F_SZ 8192
#define K_TOP 30
#define N_CAND 44

typedef short bf16x8 __attribute__((ext_vector_type(8)));
typedef float f32x4 __attribute__((ext_vector_type(4)));

// round-to-nearest-even float -> bf16 bits
__device__ __forceinline__ ushort f2bf(float f) {
  union { float f; uint32_t u; } a;
  a.f = f;
  const uint32_t r = a.u + 0x7fffu + ((a.u >> 16) & 1u);
  return (ushort)(r >> 16);
}

__device__ __forceinline__ void async16(const void* g, void* l) {
  __builtin_amdgcn_global_load_lds(
      (const __attribute__((address_space(1))) uint32_t*)g,
      (__attribute__((address_space(3))) uint32_t*)l, 16, 0, 0);
}

// ---------------------------------------------------------------------------
// Convert (x - dec_b) -> bf16, enc_w -> bf16
// ---------------------------------------------------------------------------
__global__ __launch_bounds__(256) void conv_x(const float* __restrict__ x,
                                              const float* __restrict__ dec_b,
                                              ushort* __restrict__ xh) {
  const int i = blockIdx.x * 256 + threadIdx.x;  // float4 index over B*D/4
  const float4 v = ((const float4*)x)[i];
  const float4 db = ((const float4*)dec_b)[i & (D_SZ / 4 - 1)];
  ushort4 o;
  o.x = f2bf(v.x - db.x);
  o.y = f2bf(v.y - db.y);
  o.z = f2bf(v.z - db.z);
  o.w = f2bf(v.w - db.w);
  ((ushort4*)xh)[i] = o;
}

__global__ __launch_bounds__(256) void conv_w(const float* __restrict__ w,
                                              ushort* __restrict__ wh) {
  const int i = blockIdx.x * 256 + threadIdx.x;  // float4 index over F*D/4
  const float4 v = ((const float4*)w)[i];
  ushort4 o;
  o.x = f2bf(v.x);
  o.y = f2bf(v.y);
  o.z = f2bf(v.z);
  o.w = f2bf(v.w);
  ((ushort4*)wh)[i] = o;
}

// ---------------------------------------------------------------------------
// Pass-1 encode GEMM (bf16 MFMA, m97 structure):
// pre[b,f] ~= sum_d A[b,d]*W[f,d] + enc_b[f]   (A = bf16(x-dec_b), W = bf16(enc_w))
// 128x128 tile, BK=32, 256 threads (4 waves, each 64x64 = 4x4 frags of 16x16x32).
// ---------------------------------------------------------------------------
#define GBM 128
#define GBN 128
#define GBK 32

__global__ __launch_bounds__(256) void encode_gemm_bf16(
    const ushort* __restrict__ A, const ushort* __restrict__ W,
    const float* __restrict__ enc_b, float* __restrict__ pre) {
  __shared__ ushort As[GBM * GBK];
  __shared__ ushort Bs[GBN * GBK];
  const int tid = threadIdx.x;
  const int wave = tid >> 6;
  const int lane = tid & 63;
  const int rb = blockIdx.y * GBM;
  const int cb = blockIdx.x * GBN;
  const int wm = (wave >> 1) * 64;
  const int wn = (wave & 1) * 64;

  // staging: wave handles rows [wave*32, wave*32+32), two 16-row chunks
  const int srow = wave * 32;
  const int lrow = lane >> 2;
  const int lk = (lane & 3) * 8;
  const ushort* ga0 = A + (size_t)(rb + srow + lrow) * D_SZ + lk;
  const ushort* ga1 = A + (size_t)(rb + srow + 16 + lrow) * D_SZ + lk;
  const ushort* gb0 = W + (size_t)(cb + srow + lrow) * D_SZ + lk;
  const ushort* gb1 = W + (size_t)(cb + srow + 16 + lrow) * D_SZ + lk;
  ushort* la0 = &As[srow * GBK];
  ushort* la1 = &As[(srow + 16) * GBK];
  ushort* lb0 = &Bs[srow * GBK];
  ushort* lb1 = &Bs[(srow + 16) * GBK];

  f32x4 acc[4][4];
#pragma unroll
  for (int i = 0; i < 4; i++)
#pragma unroll
    for (int j = 0; j < 4; j++) acc[i][j] = (f32x4)(0.f);

  const int fm = lane & 15;        // row within 16x16 frag
  const int fk = (lane >> 4) * 8;  // k offset (elems)

  for (int kt = 0; kt < D_SZ; kt += GBK) {
    __syncthreads();  // previous iteration's ds_reads complete
    async16(ga0 + kt, la0);
    async16(ga1 + kt, la1);
    async16(gb0 + kt, lb0);
    async16(gb1 + kt, lb1);
    __syncthreads();  // drains vmcnt(0) before barrier
    bf16x8 af[4], bfr[4];
#pragma unroll
    for (int i = 0; i < 4; i++)
      af[i] = *(const bf16x8*)&As[(wm + i * 16 + fm) * GBK + fk];
#pragma unroll
    for (int j = 0; j < 4; j++)
      bfr[j] = *(const bf16x8*)&Bs[(wn + j * 16 + fm) * GBK + fk];
#pragma unroll
    for (int i = 0; i < 4; i++)
#pragma unroll
      for (int j = 0; j < 4; j++)
        acc[i][j] = __builtin_amdgcn_mfma_f32_16x16x32_bf16(af[i], bfr[j],
                                                            acc[i][j], 0, 0, 0);
  }

  // C/D layout: col = lane&15, row = (lane>>4)*4 + reg
  const int crow0 = rb + wm + (lane >> 4) * 4;
  const int ccol0 = cb + wn + (lane & 15);
#pragma unroll
  for (int j = 0; j < 4; j++) {
    const int col = ccol0 + j * 16;
    const float eb = enc_b[col];
#pragma unroll
    for (int i = 0; i < 4; i++) {
#pragma unroll
      for (int r = 0; r < 4; r++)
        pre[(size_t)(crow0 + i * 16 + r) * F_SZ + col] = acc[i][j][r] + eb;
    }
  }
}

// ---------------------------------------------------------------------------
// Approx top-N_CAND per row -> candidate indices; zero the row afterwards.
// ---------------------------------------------------------------------------
__global__ __launch_bounds__(256) void topk_kernel(float* __restrict__ pre,
                                                   int* __restrict__ cidx) {
  __shared__ float row[F_SZ];
  __shared__ float tmax[256];
  __shared__ int targ[256];
  __shared__ float smax[256];
  __shared__ int sarg[256];
  const int b = blockIdx.x;
  const int t = threadIdx.x;
  float* prow = pre + (size_t)b * F_SZ;

#pragma unroll
  for (int q = 0; q < F_SZ / (256 * 4); q++) {
    const int i4 = (q * 256 + t) * 4;
    *(float4*)&row[i4] = *(const float4*)&prow[i4];
  }
  __syncthreads();

  const int base = t * 32;
  {
    float bv = -__builtin_inff();
    int bi = 0x7fffffff;
    for (int j = 0; j < 32; j++) {
      const int idx = base + ((j + t) & 31);
      const float v = row[idx];
      if (v > bv || (v == bv && idx < bi)) { bv = v; bi = idx; }
    }
    tmax[t] = bv; targ[t] = bi;
  }
  __syncthreads();

  for (int k = 0; k < N_CAND; k++) {
    if (t < 128) {
      float v = tmax[t]; int idx = targ[t];
      const float v2 = tmax[t + 128]; const int i2 = targ[t + 128];
      if (v2 > v || (v2 == v && i2 < idx)) { v = v2; idx = i2; }
      smax[t] = v; sarg[t] = idx;
    }
    __syncthreads();
    if (t < 64) {
      float v = smax[t]; int idx = sarg[t];
      const float v2 = smax[t + 64]; const int i2 = sarg[t + 64];
      if (v2 > v || (v2 == v && i2 < idx)) { v = v2; idx = i2; }
      for (int off = 32; off > 0; off >>= 1) {
        const float vv = __shfl_down(v, off);
        const int ii = __shfl_down(idx, off);
        if (vv > v || (vv == v && ii < idx)) { v = vv; idx = ii; }
      }
      if (t == 0) { smax[0] = v; sarg[0] = idx; }
    }
    __syncthreads();
    const int gi = sarg[0];
    if (t == 0) cidx[(size_t)b * N_CAND + k] = gi;
    if (t == (gi >> 5)) {
      row[gi] = -__builtin_inff();
      float bv = -__builtin_inff();
      int bi = 0x7fffffff;
      for (int j = 0; j < 32; j++) {
        const int idx = base + j;
        const float v = row[idx];
        if (v > bv || (v == bv && idx < bi)) { bv = v; bi = idx; }
      }
      tmax[t] = bv; targ[t] = bi;
    }
    __syncthreads();
  }

  // zero the sparse row (rerank scatters the 30 winners later)
#pragma unroll
  for (int q = 0; q < F_SZ / (256 * 4); q++) {
    const int i4 = (q * 256 + t) * 4;
    *(float4*)&prow[i4] = make_float4(0.f, 0.f, 0.f, 0.f);
  }
}

// ---------------------------------------------------------------------------
// Exact fp32 re-rank of the 44 candidates -> top-30, scatter into sparse.
// ---------------------------------------------------------------------------
__global__ __launch_bounds__(256) void rerank_kernel(
    const float* __restrict__ x, const float* __restrict__ enc_w,
    const float* __restrict__ enc_b, const float* __restrict__ dec_b,
    const int* __restrict__ cidx, float* __restrict__ sparse,
    float* __restrict__ tkv, int* __restrict__ tki) {
  __shared__ float xr[D_SZ];
  __shared__ float cv[N_CAND];
  __shared__ int ci[N_CAND];
  __shared__ float selv[K_TOP];
  __shared__ int seli[K_TOP];
  const int b = blockIdx.x;
  const int t = threadIdx.x;
  {
    const float4 xv = ((const float4*)(x + (size_t)b * D_SZ))[t];
    const float4 db = ((const float4*)dec_b)[t];
    ((float4*)xr)[t] = make_float4(xv.x - db.x, xv.y - db.y, xv.z - db.z, xv.w - db.w);
  }
  if (t < N_CAND) ci[t] = cidx[(size_t)b * N_CAND + t];
  __syncthreads();
  const int wave = t >> 6;
  const int lane = t & 63;
  for (int c = wave; c < N_CAND; c += 4) {
    const int f = ci[c];
    const float4* wr = (const float4*)(enc_w + (size_t)f * D_SZ);
    float s = 0.f;
#pragma unroll
    for (int q = 0; q < 4; q++) {
      const float4 w = wr[q * 64 + lane];
      const float4 a = ((const float4*)xr)[q * 64 + lane];
      s += a.x * w.x + a.y * w.y + a.z * w.z + a.w * w.w;
    }
#pragma unroll
    for (int off = 32; off > 0; off >>= 1) s += __shfl_down(s, off);
    if (lane == 0) cv[c] = s + enc_b[f];
  }
  __syncthreads();
  if (t == 0) {
    unsigned long long used = 0ull;
    for (int k = 0; k < K_TOP; k++) {
      float bv = -__builtin_inff();
      int bi = 0x7fffffff;
      int bc = 0;
      for (int c = 0; c < N_CAND; c++) {
        if (used & (1ull << c)) continue;
        const float v = cv[c];
        const int idx = ci[c];
        if (v > bv || (v == bv && idx < bi)) { bv = v; bi = idx; bc = c; }
      }
      used |= 1ull << bc;
      selv[k] = bv > 0.f ? bv : 0.f;
      seli[k] = bi;
    }
  }
  __syncthreads();
  if (t < K_TOP) {
    tkv[(size_t)b * K_TOP + t] = selv[t];
    tki[(size_t)b * K_TOP + t] = seli[t];
    sparse[(size_t)b * F_SZ + seli[t]] = selv[t];
  }
}

// ---------------------------------------------------------------------------
// Transpose dec_w [D, F] -> dec_wT [F, D]
// ---------------------------------------------------------------------------
__global__ __launch_bounds__(256) void transpose_kernel(const float* __restrict__ in,
                                                        float* __restrict__ out) {
  __shared__ float tile[32][33];
  const int bx = blockIdx.x * 32;
  const int by = blockIdx.y * 32;
  const int tx = threadIdx.x & 31;
  const int ty = threadIdx.x >> 5;
#pragma unroll
  for (int r = 0; r < 32; r += 8)
    tile[ty + r][tx] = in[(size_t)(by + ty + r) * F_SZ + bx + tx];
  __syncthreads();
#pragma unroll
  for (int r = 0; r < 32; r += 8)
    out[(size_t)(bx + ty + r) * D_SZ + by + tx] = tile[tx][ty + r];
}

// ---------------------------------------------------------------------------
// Decode: recon[b,:] = dec_b + sum_k v_k * dec_wT[idx_k, :]
// ---------------------------------------------------------------------------
__global__ __launch_bounds__(256) void decode_kernel(const float* __restrict__ tkv,
                                                     const int* __restrict__ tki,
                                                     const float* __restrict__ dec_wT,
                                                     const float* __restrict__ dec_b,
                                                     float* __restrict__ recon) {
  __shared__ float kv[K_TOP];
  __shared__ int ki[K_TOP];
  const int b = blockIdx.x;
  const int t = threadIdx.x;
  if (t < K_TOP) {
    kv[t] = tkv[(size_t)b * K_TOP + t];
    ki[t] = tki[(size_t)b * K_TOP + t];
  }
  __syncthreads();
  const int col = t * 4;
  float4 acc = *(const float4*)&dec_b[col];
#pragma unroll 5
  for (int k = 0; k < K_TOP; k++) {
    const float v = kv[k];
    const float4 w = *(const float4*)&dec_wT[(size_t)ki[k] * D_SZ + col];
    acc.x += v * w.x; acc.y += v * w.y; acc.z += v * w.z; acc.w += v * w.w;
  }
  *(float4*)&recon[(size_t)b * D_SZ + col] = acc;
}

// ---------------------------------------------------------------------------
extern "C" void kernel_launch(void* const* d_in, const int* in_sizes, int n_in,
                              void* d_out, int out_size, void* d_ws, size_t ws_size,
                              hipStream_t stream) {
  const float* x     = (const float*)d_in[0];  // [B, D]
  const float* enc_w = (const float*)d_in[1];  // [F, D]
  const float* enc_b = (const float*)d_in[2];  // [F]
  const float* dec_w = (const float*)d_in[3];  // [D, F]
  const float* dec_b = (const float*)d_in[4];  // [D]

  float* recon_out  = (float*)d_out;                        // [B, D]
  float* sparse_out = (float*)d_out + (size_t)B_SZ * D_SZ;  // [B, F]

  // bf16 limbs live in the recon region (67 MB; dead until decode, which runs last)
  ushort* xh = (ushort*)recon_out;                 // [B, D] bf16 (33.5 MB)
  ushort* wh = xh + (size_t)B_SZ * D_SZ;           // [F, D] bf16 (16.8 MB)

  // ws layout: tkv [B*30] f32, tki [B*30] i32, cidx [B*44] i32, dec_wT [F*D] f32
  float* tkv    = (float*)d_ws;
  int*   tki    = (int*)((char*)d_ws + (size_t)B_SZ * K_TOP * 4);
  int*   cidx   = (int*)((char*)d_ws + (size_t)2 * B_SZ * K_TOP * 4);
  float* dec_wT = (float*)((char*)d_ws + (size_t)B_SZ * (2 * K_TOP + N_CAND) * 4);

  // 1. bf16 conversions
  conv_x<<<B_SZ * D_SZ / 4 / 256, 256, 0, stream>>>(x, dec_b, xh);
  conv_w<<<F_SZ * D_SZ / 4 / 256, 256, 0, stream>>>(enc_w, wh);

  // 2. approx encode GEMM (bf16 MFMA) -> sparse region
  encode_gemm_bf16<<<dim3(F_SZ / GBN, B_SZ / GBM), 256, 0, stream>>>(xh, wh, enc_b,
                                                                     sparse_out);

  // 3. approx top-44 candidates per row, zero the sparse row
  topk_kernel<<<B_SZ, 256, 0, stream>>>(sparse_out, cidx);

  // 4. exact fp32 re-rank -> top-30, scatter exact values
  rerank_kernel<<<B_SZ, 256, 0, stream>>>(x, enc_w, enc_b, dec_b, cidx, sparse_out,
                                          tkv, tki);

  // 5. transpose dec_w, then sparse decode (overwrites xh/wh region)
  transpose_kernel<<<dim3(F_SZ / 32, D_SZ / 32), 256, 0, stream>>>(dec_w, dec_wT);
  decode_kernel<<<B_SZ, 256, 0, stream>>>(tkv, tki, dec_wT, dec_b, recon_out);
}

// Round 3
// 1837.213 us; speedup vs baseline: 3.0625x; 2.3309x over previous
//
#include <hip/hip_runtime.h>
#include <stdint.h>

#define B_SZ 16384
#define D_SZ 1024
#define F_SZ 8192
#define K_TOP 30
#define N_CAND 44     // histogram threshold rank (superset margin for exact rerank)
#define CAND_CAP 64   // max candidates kept per row
#define NBUCK 8192    // histogram bins

typedef short bf16x8 __attribute__((ext_vector_type(8)));
typedef float f32x4 __attribute__((ext_vector_type(4)));

// round-to-nearest-even float -> bf16 bits
__device__ __forceinline__ ushort f2bf(float f) {
  union { float f; uint32_t u; } a;
  a.f = f;
  const uint32_t r = a.u + 0x7fffu + ((a.u >> 16) & 1u);
  return (ushort)(r >> 16);
}

__device__ __forceinline__ void async16(const void* g, void* l) {
  __builtin_amdgcn_global_load_lds(
      (const __attribute__((address_space(1))) uint32_t*)g,
      (__attribute__((address_space(3))) uint32_t*)l, 16, 0, 0);
}

// monotone value->bucket map: width 1/512 over [-8, 8]
__device__ __forceinline__ int bk(float f) {
  int k = (int)floorf(f * 512.f) + 4096;
  k = k < 0 ? 0 : k;
  return k > (NBUCK - 1) ? (NBUCK - 1) : k;
}

// ---------------------------------------------------------------------------
// Convert (x - dec_b) -> bf16, enc_w -> bf16
// ---------------------------------------------------------------------------
__global__ __launch_bounds__(256) void conv_x(const float* __restrict__ x,
                                              const float* __restrict__ dec_b,
                                              ushort* __restrict__ xh) {
  const int i = blockIdx.x * 256 + threadIdx.x;
  const float4 v = ((const float4*)x)[i];
  const float4 db = ((const float4*)dec_b)[i & (D_SZ / 4 - 1)];
  ushort4 o;
  o.x = f2bf(v.x - db.x);
  o.y = f2bf(v.y - db.y);
  o.z = f2bf(v.z - db.z);
  o.w = f2bf(v.w - db.w);
  ((ushort4*)xh)[i] = o;
}

__global__ __launch_bounds__(256) void conv_w(const float* __restrict__ w,
                                              ushort* __restrict__ wh) {
  const int i = blockIdx.x * 256 + threadIdx.x;
  const float4 v = ((const float4*)w)[i];
  ushort4 o;
  o.x = f2bf(v.x);
  o.y = f2bf(v.y);
  o.z = f2bf(v.z);
  o.w = f2bf(v.w);
  ((ushort4*)wh)[i] = o;
}

// ---------------------------------------------------------------------------
// Approx encode GEMM (bf16 MFMA, m97 structure), 128x128 tile, BK=32.
// ---------------------------------------------------------------------------
#define GBM 128
#define GBN 128
#define GBK 32

__global__ __launch_bounds__(256) void encode_gemm_bf16(
    const ushort* __restrict__ A, const ushort* __restrict__ W,
    const float* __restrict__ enc_b, float* __restrict__ pre) {
  __shared__ ushort As[GBM * GBK];
  __shared__ ushort Bs[GBN * GBK];
  const int tid = threadIdx.x;
  const int wave = tid >> 6;
  const int lane = tid & 63;
  const int rb = blockIdx.y * GBM;
  const int cb = blockIdx.x * GBN;
  const int wm = (wave >> 1) * 64;
  const int wn = (wave & 1) * 64;

  const int srow = wave * 32;
  const int lrow = lane >> 2;
  const int lk = (lane & 3) * 8;
  const ushort* ga0 = A + (size_t)(rb + srow + lrow) * D_SZ + lk;
  const ushort* ga1 = A + (size_t)(rb + srow + 16 + lrow) * D_SZ + lk;
  const ushort* gb0 = W + (size_t)(cb + srow + lrow) * D_SZ + lk;
  const ushort* gb1 = W + (size_t)(cb + srow + 16 + lrow) * D_SZ + lk;
  ushort* la0 = &As[srow * GBK];
  ushort* la1 = &As[(srow + 16) * GBK];
  ushort* lb0 = &Bs[srow * GBK];
  ushort* lb1 = &Bs[(srow + 16) * GBK];

  f32x4 acc[4][4];
#pragma unroll
  for (int i = 0; i < 4; i++)
#pragma unroll
    for (int j = 0; j < 4; j++) acc[i][j] = (f32x4)(0.f);

  const int fm = lane & 15;
  const int fk = (lane >> 4) * 8;

  for (int kt = 0; kt < D_SZ; kt += GBK) {
    __syncthreads();
    async16(ga0 + kt, la0);
    async16(ga1 + kt, la1);
    async16(gb0 + kt, lb0);
    async16(gb1 + kt, lb1);
    __syncthreads();
    bf16x8 af[4], bfr[4];
#pragma unroll
    for (int i = 0; i < 4; i++)
      af[i] = *(const bf16x8*)&As[(wm + i * 16 + fm) * GBK + fk];
#pragma unroll
    for (int j = 0; j < 4; j++)
      bfr[j] = *(const bf16x8*)&Bs[(wn + j * 16 + fm) * GBK + fk];
#pragma unroll
    for (int i = 0; i < 4; i++)
#pragma unroll
      for (int j = 0; j < 4; j++)
        acc[i][j] = __builtin_amdgcn_mfma_f32_16x16x32_bf16(af[i], bfr[j],
                                                            acc[i][j], 0, 0, 0);
  }

  const int crow0 = rb + wm + (lane >> 4) * 4;
  const int ccol0 = cb + wn + (lane & 15);
#pragma unroll
  for (int j = 0; j < 4; j++) {
    const int col = ccol0 + j * 16;
    const float eb = enc_b[col];
#pragma unroll
    for (int i = 0; i < 4; i++) {
#pragma unroll
      for (int r = 0; r < 4; r++)
        pre[(size_t)(crow0 + i * 16 + r) * F_SZ + col] = acc[i][j][r] + eb;
    }
  }
}

// ---------------------------------------------------------------------------
// Histogram top-candidate select per row. Collects ALL indices whose approx
// value lands at-or-above the bucket where the top-down cumulative count
// reaches N_CAND (superset of approx top-N_CAND). Zeros the row afterwards.
// ---------------------------------------------------------------------------
__global__ __launch_bounds__(256) void topk_hist(float* __restrict__ pre,
                                                 int* __restrict__ cidx,
                                                 int* __restrict__ ccnt) {
  __shared__ uint32_t hist[NBUCK];  // 32 KB
  __shared__ int scan[256];
  __shared__ int Tsh;
  __shared__ int cnt;
  __shared__ int cand[CAND_CAP];
  const int b = blockIdx.x;
  const int t = threadIdx.x;
  float* prow = pre + (size_t)b * F_SZ;

#pragma unroll
  for (int q = 0; q < NBUCK / 256; q++) hist[q * 256 + t] = 0;
  if (t == 0) cnt = 0;
  __syncthreads();

  // row in registers: thread t holds float4s q*256+t (coalesced)
  float4 v[8];
#pragma unroll
  for (int q = 0; q < 8; q++) v[q] = ((const float4*)prow)[q * 256 + t];

#pragma unroll
  for (int q = 0; q < 8; q++) {
    atomicAdd(&hist[bk(v[q].x)], 1u);
    atomicAdd(&hist[bk(v[q].y)], 1u);
    atomicAdd(&hist[bk(v[q].z)], 1u);
    atomicAdd(&hist[bk(v[q].w)], 1u);
  }
  __syncthreads();

  // thread t owns a descending 32-bucket chunk; partial sums + inclusive scan
  const int cbase = NBUCK - 32 * (t + 1);
  int s = 0;
#pragma unroll
  for (int j = 0; j < 32; j++) s += (int)hist[cbase + j];
  scan[t] = s;
  __syncthreads();
  for (int off = 1; off < 256; off <<= 1) {
    const int add = (t >= off) ? scan[t - off] : 0;
    __syncthreads();
    scan[t] += add;
    __syncthreads();
  }
  const int incl = scan[t];
  const int excl = incl - s;
  if (excl < N_CAND && incl >= N_CAND) {  // unique crossing thread
    int cum = excl;
    int T = cbase;
    for (int j = 31; j >= 0; j--) {
      cum += (int)hist[cbase + j];
      if (cum >= N_CAND) { T = cbase + j; break; }
    }
    Tsh = T;
  }
  __syncthreads();
  const int T = Tsh;

  // collect candidates >= threshold bucket
#pragma unroll
  for (int q = 0; q < 8; q++) {
    const int i0 = (q * 256 + t) * 4;
    if (bk(v[q].x) >= T) { const int p = atomicAdd(&cnt, 1); if (p < CAND_CAP) cand[p] = i0; }
    if (bk(v[q].y) >= T) { const int p = atomicAdd(&cnt, 1); if (p < CAND_CAP) cand[p] = i0 + 1; }
    if (bk(v[q].z) >= T) { const int p = atomicAdd(&cnt, 1); if (p < CAND_CAP) cand[p] = i0 + 2; }
    if (bk(v[q].w) >= T) { const int p = atomicAdd(&cnt, 1); if (p < CAND_CAP) cand[p] = i0 + 3; }
  }
  __syncthreads();
  const int C = cnt < CAND_CAP ? cnt : CAND_CAP;
  if (t == 0) ccnt[b] = C;
  if (t < C) cidx[(size_t)b * CAND_CAP + t] = cand[t];

  // zero the sparse row (rerank scatters the 30 winners later)
#pragma unroll
  for (int q = 0; q < 8; q++)
    ((float4*)prow)[q * 256 + t] = make_float4(0.f, 0.f, 0.f, 0.f);
}

// ---------------------------------------------------------------------------
// Exact fp32 re-rank of C candidates -> top-30 (value desc, idx asc tiebreak),
// scatter relu'd exact values into sparse.
// ---------------------------------------------------------------------------
__global__ __launch_bounds__(256) void rerank_kernel(
    const float* __restrict__ x, const float* __restrict__ enc_w,
    const float* __restrict__ enc_b, const float* __restrict__ dec_b,
    const int* __restrict__ cidx, const int* __restrict__ ccnt,
    float* __restrict__ sparse, float* __restrict__ tkv, int* __restrict__ tki) {
  __shared__ float xr[D_SZ];
  __shared__ float cv[CAND_CAP];
  __shared__ int ci[CAND_CAP];
  __shared__ float selv[K_TOP];
  __shared__ int seli[K_TOP];
  const int b = blockIdx.x;
  const int t = threadIdx.x;
  const int C = ccnt[b];
  {
    const float4 xv = ((const float4*)(x + (size_t)b * D_SZ))[t];
    const float4 db = ((const float4*)dec_b)[t];
    ((float4*)xr)[t] = make_float4(xv.x - db.x, xv.y - db.y, xv.z - db.z, xv.w - db.w);
  }
  if (t < C) ci[t] = cidx[(size_t)b * CAND_CAP + t];
  __syncthreads();
  const int wave = t >> 6;
  const int lane = t & 63;
  for (int c = wave; c < C; c += 4) {
    const int f = ci[c];
    const float4* wr = (const float4*)(enc_w + (size_t)f * D_SZ);
    float s = 0.f;
#pragma unroll
    for (int q = 0; q < 4; q++) {
      const float4 w = wr[q * 64 + lane];
      const float4 a = ((const float4*)xr)[q * 64 + lane];
      s += a.x * w.x + a.y * w.y + a.z * w.z + a.w * w.w;
    }
#pragma unroll
    for (int off = 32; off > 0; off >>= 1) s += __shfl_down(s, off);
    if (lane == 0) cv[c] = s + enc_b[f];
  }
  __syncthreads();
  // wave-0 parallel selection: lane l holds candidate l
  if (wave == 0) {
    float val = (lane < C) ? cv[lane] : -__builtin_inff();
    int idx = (lane < C) ? ci[lane] : 0x7fffffff;
    for (int k = 0; k < K_TOP; k++) {
      float bv = val;
      int bi = idx;
#pragma unroll
      for (int off = 32; off > 0; off >>= 1) {
        const float ov = __shfl_xor(bv, off);
        const int oi = __shfl_xor(bi, off);
        if (ov > bv || (ov == bv && oi < bi)) { bv = ov; bi = oi; }
      }
      if (idx == bi) val = -__builtin_inff();  // winner lane retires (idx unique)
      if (lane == 0) {
        selv[k] = bv > 0.f ? bv : 0.f;
        seli[k] = bi;
      }
    }
  }
  __syncthreads();
  if (t < K_TOP) {
    tkv[(size_t)b * K_TOP + t] = selv[t];
    tki[(size_t)b * K_TOP + t] = seli[t];
    sparse[(size_t)b * F_SZ + seli[t]] = selv[t];
  }
}

// ---------------------------------------------------------------------------
// Transpose dec_w [D, F] -> dec_wT [F, D]
// ---------------------------------------------------------------------------
__global__ __launch_bounds__(256) void transpose_kernel(const float* __restrict__ in,
                                                        float* __restrict__ out) {
  __shared__ float tile[32][33];
  const int bx = blockIdx.x * 32;
  const int by = blockIdx.y * 32;
  const int tx = threadIdx.x & 31;
  const int ty = threadIdx.x >> 5;
#pragma unroll
  for (int r = 0; r < 32; r += 8)
    tile[ty + r][tx] = in[(size_t)(by + ty + r) * F_SZ + bx + tx];
  __syncthreads();
#pragma unroll
  for (int r = 0; r < 32; r += 8)
    out[(size_t)(bx + ty + r) * D_SZ + by + tx] = tile[tx][ty + r];
}

// ---------------------------------------------------------------------------
// Decode: recon[b,:] = dec_b + sum_k v_k * dec_wT[idx_k, :]
// ---------------------------------------------------------------------------
__global__ __launch_bounds__(256) void decode_kernel(const float* __restrict__ tkv,
                                                     const int* __restrict__ tki,
                                                     const float* __restrict__ dec_wT,
                                                     const float* __restrict__ dec_b,
                                                     float* __restrict__ recon) {
  __shared__ float kv[K_TOP];
  __shared__ int ki[K_TOP];
  const int b = blockIdx.x;
  const int t = threadIdx.x;
  if (t < K_TOP) {
    kv[t] = tkv[(size_t)b * K_TOP + t];
    ki[t] = tki[(size_t)b * K_TOP + t];
  }
  __syncthreads();
  const int col = t * 4;
  float4 acc = *(const float4*)&dec_b[col];
#pragma unroll 5
  for (int k = 0; k < K_TOP; k++) {
    const float v = kv[k];
    const float4 w = *(const float4*)&dec_wT[(size_t)ki[k] * D_SZ + col];
    acc.x += v * w.x; acc.y += v * w.y; acc.z += v * w.z; acc.w += v * w.w;
  }
  *(float4*)&recon[(size_t)b * D_SZ + col] = acc;
}

// ---------------------------------------------------------------------------
extern "C" void kernel_launch(void* const* d_in, const int* in_sizes, int n_in,
                              void* d_out, int out_size, void* d_ws, size_t ws_size,
                              hipStream_t stream) {
  const float* x     = (const float*)d_in[0];  // [B, D]
  const float* enc_w = (const float*)d_in[1];  // [F, D]
  const float* enc_b = (const float*)d_in[2];  // [F]
  const float* dec_w = (const float*)d_in[3];  // [D, F]
  const float* dec_b = (const float*)d_in[4];  // [D]

  float* recon_out  = (float*)d_out;                        // [B, D]
  float* sparse_out = (float*)d_out + (size_t)B_SZ * D_SZ;  // [B, F]

  // bf16 limbs live in the recon region (dead until decode, which runs last)
  ushort* xh = (ushort*)recon_out;        // [B, D] bf16
  ushort* wh = xh + (size_t)B_SZ * D_SZ;  // [F, D] bf16

  // ws: tkv [B*30] f32, tki [B*30] i32, ccnt [B] i32, cidx [B*64] i32, dec_wT
  float* tkv    = (float*)d_ws;
  int*   tki    = (int*)((char*)d_ws + (size_t)B_SZ * K_TOP * 4);
  int*   ccnt   = (int*)((char*)d_ws + (size_t)2 * B_SZ * K_TOP * 4);
  int*   cidx   = (int*)((char*)d_ws + (size_t)B_SZ * (2 * K_TOP + 1) * 4);
  float* dec_wT = (float*)((char*)d_ws + (size_t)B_SZ * (2 * K_TOP + 1 + CAND_CAP) * 4);

  conv_x<<<B_SZ * D_SZ / 4 / 256, 256, 0, stream>>>(x, dec_b, xh);
  conv_w<<<F_SZ * D_SZ / 4 / 256, 256, 0, stream>>>(enc_w, wh);

  encode_gemm_bf16<<<dim3(F_SZ / GBN, B_SZ / GBM), 256, 0, stream>>>(xh, wh, enc_b,
                                                                     sparse_out);

  topk_hist<<<B_SZ, 256, 0, stream>>>(sparse_out, cidx, ccnt);

  rerank_kernel<<<B_SZ, 256, 0, stream>>>(x, enc_w, enc_b, dec_b, cidx, ccnt,
                                          sparse_out, tkv, tki);

  transpose_kernel<<<dim3(F_SZ / 32, D_SZ / 32), 256, 0, stream>>>(dec_w, dec_wT);
  decode_kernel<<<B_SZ, 256, 0, stream>>>(tkv, tki, dec_wT, dec_b, recon_out);
}